// Round 5
// baseline (1614.347 us; speedup 1.0000x reference)
//
#include <hip/hip_runtime.h>
#include <hip/hip_bf16.h>
#include <math.h>

#define BB 2
#define SS 2048
#define EE 768
#define HH 12
#define DD 64
#define MM (BB*SS)          // 4096 rows
#define BH (BB*HH)          // 24 heads total
#define NM ((size_t)MM*EE)  // 3145728 elements per [B,S,E] buffer

// ---------------- helpers ----------------
__device__ __forceinline__ float wave_sum64(float v) {
#pragma unroll
  for (int off = 32; off > 0; off >>= 1) v += __shfl_down(v, off, 64);
  return v;
}

// ---------------- 0. zero a float4-aligned buffer ----------------
__global__ __launch_bounds__(256) void k_zero(float4* __restrict__ p) {
  p[(size_t)blockIdx.x * 256 + threadIdx.x] = make_float4(0.f, 0.f, 0.f, 0.f);
}

// ---------------- 1. row l2-norm over E ----------------
__global__ __launch_bounds__(256) void k_rownorm(const float* __restrict__ x,
                                                 float* __restrict__ o) {
  int row = blockIdx.x;
  int tid = threadIdx.x;
  const float* xr = x + (size_t)row * EE;
  float* orow = o + (size_t)row * EE;
  float v0 = xr[tid], v1 = xr[tid + 256], v2 = xr[tid + 512];
  float ss = v0 * v0 + v1 * v1 + v2 * v2;
  ss = wave_sum64(ss);
  __shared__ float red[4];
  if ((tid & 63) == 0) red[tid >> 6] = ss;
  __syncthreads();
  float tot = red[0] + red[1] + red[2] + red[3];
  float sc = 1.0f / fmaxf(sqrtf(tot), 1e-12f);
  orow[tid] = v0 * sc; orow[tid + 256] = v1 * sc; orow[tid + 512] = v2 * sc;
}

// ---------------- 2. QKV GEMM: [4096x768]@[768x768]+bias -> head-major ----------------
__global__ __launch_bounds__(256) void k_gemm_qkv(
    const float* __restrict__ A,
    const float* __restrict__ W0, const float* __restrict__ W1, const float* __restrict__ W2,
    const float* __restrict__ b0, const float* __restrict__ b1, const float* __restrict__ b2,
    float* __restrict__ o0, float* __restrict__ o1, float* __restrict__ o2) {
  int z = blockIdx.z;
  const float* W    = (z == 0) ? W0 : (z == 1) ? W1 : W2;
  const float* bias = (z == 0) ? b0 : (z == 1) ? b1 : b2;
  float* out        = (z == 0) ? o0 : (z == 1) ? o1 : o2;
  int n0 = blockIdx.x * 64, m0 = blockIdx.y * 64;
  __shared__ float As[16][65];
  __shared__ float Bs[16][65];
  int tid = threadIdx.x;
  int ty = tid >> 4, tx = tid & 15;
  int lar = tid >> 2, lac = (tid & 3) << 2;
  float c[4][4] = {};
  for (int k0 = 0; k0 < EE; k0 += 16) {
    float4 a4 = *(const float4*)(A + (size_t)(m0 + lar) * EE + k0 + lac);
    float4 b4 = *(const float4*)(W + (size_t)(k0 + ty) * EE + n0 + (tx << 2));
    __syncthreads();
    As[lac + 0][lar] = a4.x; As[lac + 1][lar] = a4.y;
    As[lac + 2][lar] = a4.z; As[lac + 3][lar] = a4.w;
    Bs[ty][(tx << 2) + 0] = b4.x; Bs[ty][(tx << 2) + 1] = b4.y;
    Bs[ty][(tx << 2) + 2] = b4.z; Bs[ty][(tx << 2) + 3] = b4.w;
    __syncthreads();
#pragma unroll
    for (int kk = 0; kk < 16; ++kk) {
      float a[4], b_[4];
#pragma unroll
      for (int i = 0; i < 4; ++i) a[i] = As[kk][(ty << 2) + i];
#pragma unroll
      for (int j = 0; j < 4; ++j) b_[j] = Bs[kk][(tx << 2) + j];
#pragma unroll
      for (int i = 0; i < 4; ++i)
#pragma unroll
        for (int j = 0; j < 4; ++j) c[i][j] = fmaf(a[i], b_[j], c[i][j]);
    }
  }
#pragma unroll
  for (int i = 0; i < 4; ++i) {
    int row = m0 + (ty << 2) + i;
    int b_ = row >> 11;          // row / 2048
    int s = row & 2047;
#pragma unroll
    for (int j = 0; j < 4; ++j) {
      int n = n0 + (tx << 2) + j;
      int h = n >> 6, d = n & 63;
      out[(((size_t)b_ * HH + h) * SS + s) * DD + d] = c[i][j] + bias[n];
    }
  }
}

// ---------------- 3. per-head l2norm of q,k (vectors of 64) ----------------
__global__ __launch_bounds__(256) void k_headnorm(float* __restrict__ q,
                                                  float* __restrict__ k) {
  int gid = blockIdx.x * 4 + (threadIdx.x >> 6);
  int lane = threadIdx.x & 63;
  const int NV = BH * SS;  // 49152 vectors per array
  float* p = (gid < NV) ? (q + (size_t)gid * DD) : (k + (size_t)(gid - NV) * DD);
  float val = p[lane];
  float ss = val * val;
#pragma unroll
  for (int off = 32; off > 0; off >>= 1) ss += __shfl_xor(ss, off, 64);
  p[lane] = val / fmaxf(sqrtf(ss), 1e-12f);
}

// score(x) = exp(-acos(clip(x))^2)
__device__ __forceinline__ float score_of(float x) {
  float cc = fminf(fmaxf(x, -(1.0f - 1e-7f)), 1.0f - 1e-7f);
  float g = acosf(cc);
  return __expf(-g * g);
}

// ---------------- 4. colsum pass: partial[bh][s_tile][t] ----------------
__global__ __launch_bounds__(256) void k_colsum(const float* __restrict__ q,
                                                const float* __restrict__ kk_,
                                                float* __restrict__ partial) {
  int bh = blockIdx.x, st = blockIdx.y;
  __shared__ float4 q4[64][17];
  __shared__ float4 k4[64][17];
  __shared__ float red[16][64];
  int tid = threadIdx.x;
  int ty = tid >> 4, tx = tid & 15;
  const float4* qbase = (const float4*)(q + ((size_t)bh * SS + st * 64) * DD);
#pragma unroll
  for (int t = 0; t < 4; ++t) { int fi = tid + t * 256; q4[fi >> 4][fi & 15] = qbase[fi]; }
  for (int tt = 0; tt < 32; ++tt) {
    const float4* kbase = (const float4*)(kk_ + ((size_t)bh * SS + tt * 64) * DD);
    __syncthreads();
#pragma unroll
    for (int t = 0; t < 4; ++t) { int fi = tid + t * 256; k4[fi >> 4][fi & 15] = kbase[fi]; }
    __syncthreads();
    float c[4][4] = {};
#pragma unroll
    for (int dd = 0; dd < 16; ++dd) {
      float4 qa[4], kb[4];
#pragma unroll
      for (int i = 0; i < 4; ++i) qa[i] = q4[(ty << 2) + i][dd];
#pragma unroll
      for (int j = 0; j < 4; ++j) kb[j] = k4[(tx << 2) + j][dd];
#pragma unroll
      for (int i = 0; i < 4; ++i)
#pragma unroll
        for (int j = 0; j < 4; ++j)
          c[i][j] += qa[i].x * kb[j].x + qa[i].y * kb[j].y +
                     qa[i].z * kb[j].z + qa[i].w * kb[j].w;
    }
    float colp[4] = {0.f, 0.f, 0.f, 0.f};
#pragma unroll
    for (int i = 0; i < 4; ++i)
#pragma unroll
      for (int j = 0; j < 4; ++j) colp[j] += score_of(c[i][j]);
#pragma unroll
    for (int j = 0; j < 4; ++j) red[ty][(tx << 2) + j] = colp[j];
    __syncthreads();
    if (tid < 64) {
      float s_ = 0.f;
#pragma unroll
      for (int r = 0; r < 16; ++r) s_ += red[r][tid];
      partial[((size_t)bh * 32 + st) * SS + tt * 64 + tid] = s_;
    }
  }
}

// ---------------- 5. reduce partials -> cw = colsum^-1/2 ----------------
__global__ __launch_bounds__(256) void k_colreduce(const float* __restrict__ partial,
                                                   float* __restrict__ cw) {
  int g = blockIdx.x * 256 + threadIdx.x;  // < BH*SS
  int bh = g >> 11, t = g & 2047;
  float s = 0.f;
#pragma unroll 4
  for (int st = 0; st < 32; ++st) s += partial[((size_t)bh * 32 + st) * SS + t];
  cw[g] = 1.0f / sqrtf(s);
}

// ---------------- 6. pass 2: weights + PV, write attn_out ----------------
__global__ __launch_bounds__(256) void k_attn2(const float* __restrict__ q,
                                               const float* __restrict__ kk_,
                                               const float* __restrict__ v,
                                               const float* __restrict__ cw,
                                               float* __restrict__ ao) {
  int bh = blockIdx.x, st = blockIdx.y;
  __shared__ float4 q4[64][17];
  __shared__ float4 k4[64][17];
  int tid = threadIdx.x, ty = tid >> 4, tx = tid & 15;
  int lane = tid & 63;
  int grpbase = lane & 48;  // first lane of my 16-lane row-group within the wave
  const float4* qbase = (const float4*)(q + ((size_t)bh * SS + st * 64) * DD);
#pragma unroll
  for (int t = 0; t < 4; ++t) { int fi = tid + t * 256; q4[fi >> 4][fi & 15] = qbase[fi]; }
  const float* cwb = cw + bh * SS;
  float4 acc[4];
#pragma unroll
  for (int i = 0; i < 4; ++i) acc[i] = make_float4(0.f, 0.f, 0.f, 0.f);
  float rowp[4] = {0.f, 0.f, 0.f, 0.f};
  for (int tt = 0; tt < 32; ++tt) {
    const float4* kbase = (const float4*)(kk_ + ((size_t)bh * SS + tt * 64) * DD);
    const float4* vbase = (const float4*)(v + ((size_t)bh * SS + tt * 64) * DD);
    __syncthreads();
#pragma unroll
    for (int t = 0; t < 4; ++t) { int fi = tid + t * 256; k4[fi >> 4][fi & 15] = kbase[fi]; }
    __syncthreads();
    float c[4][4] = {};
#pragma unroll
    for (int dd = 0; dd < 16; ++dd) {
      float4 qa[4], kb[4];
#pragma unroll
      for (int i = 0; i < 4; ++i) qa[i] = q4[(ty << 2) + i][dd];
#pragma unroll
      for (int j = 0; j < 4; ++j) kb[j] = k4[(tx << 2) + j][dd];
#pragma unroll
      for (int i = 0; i < 4; ++i)
#pragma unroll
        for (int j = 0; j < 4; ++j)
          c[i][j] += qa[i].x * kb[j].x + qa[i].y * kb[j].y +
                     qa[i].z * kb[j].z + qa[i].w * kb[j].w;
    }
    // weights for this thread's 4 rows x 4 t-cols (t = tt*64 + tx*4 + j)
    float w[4][4];
    float cj[4];
#pragma unroll
    for (int j = 0; j < 4; ++j) cj[j] = cwb[tt * 64 + (tx << 2) + j];
#pragma unroll
    for (int i = 0; i < 4; ++i)
#pragma unroll
      for (int j = 0; j < 4; ++j) {
        float ww = score_of(c[i][j]) * cj[j];
        w[i][j] = ww;
        rowp[i] += ww;
      }
    // PV: broadcast w[row][t=j] from lane grpbase+(j>>2); V straight from global
#pragma unroll
    for (int j = 0; j < 64; ++j) {
      int sl = grpbase + (j >> 2);
      float4 vv = vbase[j * 16 + tx];
#pragma unroll
      for (int i = 0; i < 4; ++i) {
        float wij = __shfl(w[i][j & 3], sl, 64);
        acc[i].x = fmaf(wij, vv.x, acc[i].x);
        acc[i].y = fmaf(wij, vv.y, acc[i].y);
        acc[i].z = fmaf(wij, vv.z, acc[i].z);
        acc[i].w = fmaf(wij, vv.w, acc[i].w);
      }
    }
  }
  // row denominator: sum rowp across the 16 lanes of this row-group (same wave)
#pragma unroll
  for (int off = 8; off > 0; off >>= 1) {
#pragma unroll
    for (int i = 0; i < 4; ++i) rowp[i] += __shfl_xor(rowp[i], off, 64);
  }
  float* aobase = ao + ((size_t)bh * SS + st * 64) * DD;
#pragma unroll
  for (int i = 0; i < 4; ++i) {
    int srow = (ty << 2) + i;
    float inv = 1.0f / fmaxf(rowp[i], 1e-12f);
    float4 o;
    o.x = acc[i].x * inv; o.y = acc[i].y * inv;
    o.z = acc[i].z * inv; o.w = acc[i].w * inv;
    *(float4*)(aobase + (size_t)srow * DD + (tx << 2)) = o;
  }
}

// ---------------- 7. output GEMM + bias + residual ----------------
__global__ __launch_bounds__(256) void k_gemm_out(const float* __restrict__ A,
                                                  const float* __restrict__ W,
                                                  const float* __restrict__ bias,
                                                  const float* __restrict__ hid,
                                                  float* __restrict__ y) {
  int n0 = blockIdx.x * 64, m0 = blockIdx.y * 64;
  __shared__ float As[16][65];
  __shared__ float Bs[16][65];
  int tid = threadIdx.x;
  int ty = tid >> 4, tx = tid & 15;
  int lar = tid >> 2, lac = (tid & 3) << 2;
  float c[4][4] = {};
  for (int k0 = 0; k0 < EE; k0 += 16) {
    float4 a4 = *(const float4*)(A + (size_t)(m0 + lar) * EE + k0 + lac);
    float4 b4 = *(const float4*)(W + (size_t)(k0 + ty) * EE + n0 + (tx << 2));
    __syncthreads();
    As[lac + 0][lar] = a4.x; As[lac + 1][lar] = a4.y;
    As[lac + 2][lar] = a4.z; As[lac + 3][lar] = a4.w;
    Bs[ty][(tx << 2) + 0] = b4.x; Bs[ty][(tx << 2) + 1] = b4.y;
    Bs[ty][(tx << 2) + 2] = b4.z; Bs[ty][(tx << 2) + 3] = b4.w;
    __syncthreads();
#pragma unroll
    for (int kk = 0; kk < 16; ++kk) {
      float a[4], b_[4];
#pragma unroll
      for (int i = 0; i < 4; ++i) a[i] = As[kk][(ty << 2) + i];
#pragma unroll
      for (int j = 0; j < 4; ++j) b_[j] = Bs[kk][(tx << 2) + j];
#pragma unroll
      for (int i = 0; i < 4; ++i)
#pragma unroll
        for (int j = 0; j < 4; ++j) c[i][j] = fmaf(a[i], b_[j], c[i][j]);
    }
  }
#pragma unroll
  for (int i = 0; i < 4; ++i) {
    int row = m0 + (ty << 2) + i;
    const float* hrow = hid + (size_t)row * EE;
    float* yrow = y + (size_t)row * EE;
#pragma unroll
    for (int j = 0; j < 4; ++j) {
      int n = n0 + (tx << 2) + j;
      yrow[n] = c[i][j] + bias[n] + hrow[n];
    }
  }
}

// ---------------- 8. LayerNorm -> float32 out ----------------
__global__ __launch_bounds__(256) void k_ln(const float* __restrict__ y,
                                            const float* __restrict__ g,
                                            const float* __restrict__ b,
                                            float* __restrict__ out) {
  int row = blockIdx.x;
  int tid = threadIdx.x;
  const float* yr = y + (size_t)row * EE;
  float v0 = yr[tid], v1 = yr[tid + 256], v2 = yr[tid + 512];
  float s1 = v0 + v1 + v2;
  float s2 = v0 * v0 + v1 * v1 + v2 * v2;
#pragma unroll
  for (int off = 32; off > 0; off >>= 1) {
    s1 += __shfl_down(s1, off, 64);
    s2 += __shfl_down(s2, off, 64);
  }
  __shared__ float r1[4], r2[4];
  if ((tid & 63) == 0) { r1[tid >> 6] = s1; r2[tid >> 6] = s2; }
  __syncthreads();
  float S1 = r1[0] + r1[1] + r1[2] + r1[3];
  float S2 = r2[0] + r2[1] + r2[2] + r2[3];
  float mu = S1 * (1.0f / 768.0f);
  float var = fmaxf(S2 * (1.0f / 768.0f) - mu * mu, 0.0f);
  float rstd = 1.0f / sqrtf(var + 1e-12f);
  float* orow = out + (size_t)row * EE;
  orow[tid]       = (v0 - mu) * rstd * g[tid]       + b[tid];
  orow[tid + 256] = (v1 - mu) * rstd * g[tid + 256] + b[tid + 256];
  orow[tid + 512] = (v2 - mu) * rstd * g[tid + 512] + b[tid + 512];
}

extern "C" void kernel_launch(void* const* d_in, const int* in_sizes, int n_in,
                              void* d_out, int out_size, void* d_ws, size_t ws_size,
                              hipStream_t stream) {
  const float* hidden = (const float*)d_in[0];
  const float* Wq = (const float*)d_in[1];
  const float* bq = (const float*)d_in[2];
  const float* Wk = (const float*)d_in[3];
  const float* bk = (const float*)d_in[4];
  const float* Wv = (const float*)d_in[5];
  const float* bv = (const float*)d_in[6];
  const float* Wo = (const float*)d_in[7];
  const float* bo = (const float*)d_in[8];
  const float* lng = (const float*)d_in[9];
  const float* lnb = (const float*)d_in[10];
  float* out = (float*)d_out;   // reference output dtype is float32

  float* ws = (float*)d_ws;
  size_t need = (5 * NM + (size_t)BH * SS) * sizeof(float);
  if (ws_size < need) return;

  float* hs_n = ws;            // [B,S,E] normalized hidden; reused: colsum partials, then y
  float* q    = ws + 1 * NM;   // [BH,S,D]
  float* k    = ws + 2 * NM;
  float* v    = ws + 3 * NM;
  float* ao   = ws + 4 * NM;   // attn_out only (zeroed before attn2)
  float* cw   = ws + 5 * NM;   // [BH,S]
  float* partial = hs_n;       // BH*32*SS = 1.57M floats fits; hs_n only needed by gemm_qkv
  float* y    = hs_n;          // gemm_out fully overwrites

  hipLaunchKernelGGL(k_rownorm, dim3(MM), dim3(256), 0, stream, hidden, hs_n);
  hipLaunchKernelGGL(k_gemm_qkv, dim3(EE / 64, MM / 64, 3), dim3(256), 0, stream,
                     hs_n, Wq, Wk, Wv, bq, bk, bv, q, k, v);
  hipLaunchKernelGGL(k_headnorm, dim3(2 * BH * SS / 4), dim3(256), 0, stream, q, k);
  hipLaunchKernelGGL(k_colsum, dim3(BH, 32), dim3(256), 0, stream, q, k, partial);
  hipLaunchKernelGGL(k_colreduce, dim3(BH * SS / 256), dim3(256), 0, stream, partial, cw);
  hipLaunchKernelGGL(k_zero, dim3(NM / 4 / 256), dim3(256), 0, stream, (float4*)ao);
  hipLaunchKernelGGL(k_attn2, dim3(BH, 32), dim3(256), 0, stream, q, k, v, cw, ao);
  hipLaunchKernelGGL(k_gemm_out, dim3(EE / 64, MM / 64), dim3(256), 0, stream,
                     ao, Wo, bo, hidden, y);
  hipLaunchKernelGGL(k_ln, dim3(MM), dim3(256), 0, stream, y, lng, lnb, out);
}

// Round 6
// 616.539 us; speedup vs baseline: 2.6184x; 2.6184x over previous
//
#include <hip/hip_runtime.h>
#include <hip/hip_bf16.h>
#include <math.h>

#define BB 2
#define SS 2048
#define EE 768
#define HH 12
#define DD 64
#define MM (BB*SS)          // 4096 rows
#define BH (BB*HH)          // 24 heads total
#define NM ((size_t)MM*EE)  // 3145728 elements per [B,S,E] buffer

typedef __attribute__((ext_vector_type(8))) short bf16x8;   // 8 bf16 in 4 VGPR
typedef __attribute__((ext_vector_type(4))) float f32x4;    // MFMA C/D frag

// ---------------- helpers ----------------
__device__ __forceinline__ float wave_sum64(float v) {
#pragma unroll
  for (int off = 32; off > 0; off >>= 1) v += __shfl_down(v, off, 64);
  return v;
}

// RNE pack two floats -> packed bf16 pair (lo = x)
__device__ __forceinline__ unsigned int pack_bf2(float x, float y) {
  unsigned int a = __float_as_uint(x), b = __float_as_uint(y);
  a += 0x7fffu + ((a >> 16) & 1u);
  b += 0x7fffu + ((b >> 16) & 1u);
  return (a >> 16) | (b & 0xffff0000u);
}

// score(x) = exp(-acos(clip(x))^2), fast: A&S 4.4.45 4-term (|err acos| <= 6.8e-5)
__device__ __forceinline__ float score_fast(float x) {
  float a = fminf(fabsf(x), 0.9999999f);
  float r = sqrtf(1.0f - a);
  float p = fmaf(a, fmaf(a, fmaf(a, -0.0187293f, 0.0742610f), -0.2121144f), 1.5707288f);
  float gp = r * p;
  float g = (x < 0.0f) ? (3.14159274f - gp) : gp;
  return __expf(-g * g);
}

// ---------------- 1. row l2-norm over E ----------------
__global__ __launch_bounds__(256) void k_rownorm(const float* __restrict__ x,
                                                 float* __restrict__ o) {
  int row = blockIdx.x;
  int tid = threadIdx.x;
  const float* xr = x + (size_t)row * EE;
  float* orow = o + (size_t)row * EE;
  float v0 = xr[tid], v1 = xr[tid + 256], v2 = xr[tid + 512];
  float ss = v0 * v0 + v1 * v1 + v2 * v2;
  ss = wave_sum64(ss);
  __shared__ float red[4];
  if ((tid & 63) == 0) red[tid >> 6] = ss;
  __syncthreads();
  float tot = red[0] + red[1] + red[2] + red[3];
  float sc = 1.0f / fmaxf(sqrtf(tot), 1e-12f);
  orow[tid] = v0 * sc; orow[tid + 256] = v1 * sc; orow[tid + 512] = v2 * sc;
}

// ---------------- 2. QKV GEMM (fp32 vector, unchanged) ----------------
__global__ __launch_bounds__(256) void k_gemm_qkv(
    const float* __restrict__ A,
    const float* __restrict__ W0, const float* __restrict__ W1, const float* __restrict__ W2,
    const float* __restrict__ b0, const float* __restrict__ b1, const float* __restrict__ b2,
    float* __restrict__ o0, float* __restrict__ o1, float* __restrict__ o2) {
  int z = blockIdx.z;
  const float* W    = (z == 0) ? W0 : (z == 1) ? W1 : W2;
  const float* bias = (z == 0) ? b0 : (z == 1) ? b1 : b2;
  float* out        = (z == 0) ? o0 : (z == 1) ? o1 : o2;
  int n0 = blockIdx.x * 64, m0 = blockIdx.y * 64;
  __shared__ float As[16][65];
  __shared__ float Bs[16][65];
  int tid = threadIdx.x;
  int ty = tid >> 4, tx = tid & 15;
  int lar = tid >> 2, lac = (tid & 3) << 2;
  float c[4][4] = {};
  for (int k0 = 0; k0 < EE; k0 += 16) {
    float4 a4 = *(const float4*)(A + (size_t)(m0 + lar) * EE + k0 + lac);
    float4 b4 = *(const float4*)(W + (size_t)(k0 + ty) * EE + n0 + (tx << 2));
    __syncthreads();
    As[lac + 0][lar] = a4.x; As[lac + 1][lar] = a4.y;
    As[lac + 2][lar] = a4.z; As[lac + 3][lar] = a4.w;
    Bs[ty][(tx << 2) + 0] = b4.x; Bs[ty][(tx << 2) + 1] = b4.y;
    Bs[ty][(tx << 2) + 2] = b4.z; Bs[ty][(tx << 2) + 3] = b4.w;
    __syncthreads();
#pragma unroll
    for (int kk = 0; kk < 16; ++kk) {
      float a[4], b_[4];
#pragma unroll
      for (int i = 0; i < 4; ++i) a[i] = As[kk][(ty << 2) + i];
#pragma unroll
      for (int j = 0; j < 4; ++j) b_[j] = Bs[kk][(tx << 2) + j];
#pragma unroll
      for (int i = 0; i < 4; ++i)
#pragma unroll
        for (int j = 0; j < 4; ++j) c[i][j] = fmaf(a[i], b_[j], c[i][j]);
    }
  }
#pragma unroll
  for (int i = 0; i < 4; ++i) {
    int row = m0 + (ty << 2) + i;
    int b_ = row >> 11;
    int s = row & 2047;
#pragma unroll
    for (int j = 0; j < 4; ++j) {
      int n = n0 + (tx << 2) + j;
      int h = n >> 6, d = n & 63;
      out[(((size_t)b_ * HH + h) * SS + s) * DD + d] = c[i][j] + bias[n];
    }
  }
}

// ---------------- 3. per-head l2norm of q,k (fp32 in-place) ----------------
__global__ __launch_bounds__(256) void k_headnorm(float* __restrict__ q,
                                                  float* __restrict__ k) {
  int gid = blockIdx.x * 4 + (threadIdx.x >> 6);
  int lane = threadIdx.x & 63;
  const int NV = BH * SS;
  float* p = (gid < NV) ? (q + (size_t)gid * DD) : (k + (size_t)(gid - NV) * DD);
  float val = p[lane];
  float ss = val * val;
#pragma unroll
  for (int off = 32; off > 0; off >>= 1) ss += __shfl_xor(ss, off, 64);
  p[lane] = val / fmaxf(sqrtf(ss), 1e-12f);
}

// ---------------- 4. fp32 -> packed bf16 for q,k,v ----------------
__global__ __launch_bounds__(256) void k_tobf16(const float* __restrict__ qf,
                                                const float* __restrict__ kf,
                                                const float* __restrict__ vf,
                                                unsigned int* __restrict__ qb,
                                                unsigned int* __restrict__ kb,
                                                unsigned int* __restrict__ vb) {
  const size_t H2 = NM / 2;
  size_t gid = (size_t)blockIdx.x * 256 + threadIdx.x;  // < 3*H2
  const float* src; unsigned int* dst; size_t off;
  if (gid < H2)          { src = qf; dst = qb; off = gid; }
  else if (gid < 2 * H2) { src = kf; dst = kb; off = gid - H2; }
  else                   { src = vf; dst = vb; off = gid - 2 * H2; }
  float2 xy = *(const float2*)(src + off * 2);
  dst[off] = pack_bf2(xy.x, xy.y);
}

// ---------------- 5. colsum pass (MFMA): block = (bh, t-tile of 64) -> cw ----------------
// C[s][t] = mfma(A=Q, B=K^T). A/B frag (16x16x32): m(or n)=lane&15, k=(lane>>4)*8+j.
// C (m89-verified): col = lane&15, row = (lane>>4)*4 + reg.
__global__ __launch_bounds__(256) void k_colsum_mfma(const ushort* __restrict__ qbf,
                                                     const ushort* __restrict__ kbf,
                                                     float* __restrict__ cwout) {
  int bh = blockIdx.x, ttile = blockIdx.y;
  __shared__ __align__(16) ushort K_lds[64][72];   // [t][d] bf16, stride 144B (bank-even)
  __shared__ float scs[4][4][16];
  int tid = threadIdx.x;
  int w = tid >> 6, l = tid & 63;
  int li = l & 15, g = l >> 4;
  // stage K tile once
  const ushort* kt = kbf + ((size_t)bh * SS + ttile * 64) * 64;
#pragma unroll
  for (int i = 0; i < 2; ++i) {
    int idx = i * 256 + tid; int t = idx >> 3, c = idx & 7;
    *(bf16x8*)&K_lds[t][c * 8] = *(const bf16x8*)(kt + t * 64 + c * 8);
  }
  __syncthreads();
  // hoist K B-frags: B[k=d][n=t]: t = u*16+li, d = kc*32 + 8g + j
  bf16x8 kb[4][2];
#pragma unroll
  for (int u = 0; u < 4; ++u)
#pragma unroll
    for (int kc = 0; kc < 2; ++kc)
      kb[u][kc] = *(const bf16x8*)&K_lds[u * 16 + li][kc * 32 + 8 * g];
  float cacc[4] = {0.f, 0.f, 0.f, 0.f};
  for (int it = 0; it < 32; ++it) {
    int s0 = (it * 4 + w) * 16;
    const ushort* qrow = qbf + ((size_t)bh * SS + s0 + li) * 64;
    bf16x8 qa0 = *(const bf16x8*)(qrow + 0 * 32 + 8 * g);
    bf16x8 qa1 = *(const bf16x8*)(qrow + 1 * 32 + 8 * g);
#pragma unroll
    for (int u = 0; u < 4; ++u) {
      f32x4 cf = {0.f, 0.f, 0.f, 0.f};
      cf = __builtin_amdgcn_mfma_f32_16x16x32_bf16(qa0, kb[u][0], cf, 0, 0, 0);
      cf = __builtin_amdgcn_mfma_f32_16x16x32_bf16(qa1, kb[u][1], cf, 0, 0, 0);
      float s_ = score_fast(cf[0]) + score_fast(cf[1]) +
                 score_fast(cf[2]) + score_fast(cf[3]);
      cacc[u] += s_;   // partial over this lane's 4 s-rows
    }
  }
  // sum the 16 s-rows (4 lane-groups) of this wave
#pragma unroll
  for (int u = 0; u < 4; ++u) {
    cacc[u] += __shfl_xor(cacc[u], 16, 64);
    cacc[u] += __shfl_xor(cacc[u], 32, 64);
  }
  if (l < 16) {
#pragma unroll
    for (int u = 0; u < 4; ++u) scs[w][u][l] = cacc[u];
  }
  __syncthreads();
  if (tid < 64) {
    int t16 = tid & 15, u = tid >> 4;
    float s_ = scs[0][u][t16] + scs[1][u][t16] + scs[2][u][t16] + scs[3][u][t16];
    cwout[(size_t)bh * SS + ttile * 64 + u * 16 + t16] = rsqrtf(s_);
  }
}

// ---------------- 6. attention pass (MFMA): QK^T -> score*cw -> rowsum + PV ----------------
// QK^T as C[t][s] = mfma(K, Q); PV as O'[d][s] = mfma(V^T, W~).
__global__ __launch_bounds__(256) void k_attn_mfma(const ushort* __restrict__ qbf,
                                                   const ushort* __restrict__ kbf,
                                                   const ushort* __restrict__ vbf,
                                                   const float* __restrict__ cw,
                                                   float* __restrict__ ao) {
  int bh = blockIdx.x, stile = blockIdx.y;
  __shared__ __align__(16) ushort K_lds[64][72];        // [t][d] bf16
  __shared__ __align__(16) unsigned int vt32[64][36];   // [d][t-pair] packed bf16x2
  __shared__ float cw_lds[64];
  int tid = threadIdx.x;
  int w = tid >> 6, l = tid & 63;
  int li = l & 15, g = l >> 4;
  // persistent Q B-frags: B[k=d][n=s]: s = s0w+li, d = kc*32+8g+j
  const ushort* qrow = qbf + ((size_t)bh * SS + stile * 64 + w * 16 + li) * 64;
  bf16x8 qb0 = *(const bf16x8*)(qrow + 0 * 32 + 8 * g);
  bf16x8 qb1 = *(const bf16x8*)(qrow + 1 * 32 + 8 * g);
  f32x4 oacc[4];
#pragma unroll
  for (int dt = 0; dt < 4; ++dt) oacc[dt] = (f32x4){0.f, 0.f, 0.f, 0.f};
  float rp = 0.f;
  for (int tt = 0; tt < 32; ++tt) {
    const ushort* kt = kbf + ((size_t)bh * SS + tt * 64) * 64;
    const ushort* vt = vbf + ((size_t)bh * SS + tt * 64) * 64;
    __syncthreads();
    // stage K
#pragma unroll
    for (int i = 0; i < 2; ++i) {
      int idx = i * 256 + tid; int t = idx >> 3, c = idx & 7;
      *(bf16x8*)&K_lds[t][c * 8] = *(const bf16x8*)(kt + t * 64 + c * 8);
    }
    // stage V transposed (pair-packed): thread handles t-pair tp, d-chunk dc
    {
      int tp = tid & 31, dc = tid >> 5;
      const ushort* r0 = vt + (2 * tp) * 64 + dc * 8;
      bf16x8 a = *(const bf16x8*)r0;
      bf16x8 b = *(const bf16x8*)(r0 + 64);
#pragma unroll
      for (int dj = 0; dj < 8; ++dj)
        vt32[dc * 8 + dj][tp] =
            (unsigned int)(unsigned short)a[dj] |
            ((unsigned int)(unsigned short)b[dj] << 16);
    }
    if (tid < 64) cw_lds[tid] = cw[(size_t)bh * SS + tt * 64 + tid];
    __syncthreads();
    // QK^T: 4 t-subtiles; C rows t = u*16 + 4g + reg, col s = li
    f32x4 wsc[4];
#pragma unroll
    for (int u = 0; u < 4; ++u) {
      bf16x8 ka0 = *(const bf16x8*)&K_lds[u * 16 + li][0 * 32 + 8 * g];
      bf16x8 ka1 = *(const bf16x8*)&K_lds[u * 16 + li][1 * 32 + 8 * g];
      f32x4 cf = {0.f, 0.f, 0.f, 0.f};
      cf = __builtin_amdgcn_mfma_f32_16x16x32_bf16(ka0, qb0, cf, 0, 0, 0);
      cf = __builtin_amdgcn_mfma_f32_16x16x32_bf16(ka1, qb1, cf, 0, 0, 0);
#pragma unroll
      for (int r = 0; r < 4; ++r) {
        float sc = score_fast(cf[r]) * cw_lds[u * 16 + 4 * g + r];
        cf[r] = sc;
        rp += sc;
      }
      wsc[u] = cf;
    }
    // PV: 2 k-chunks of 32 t
#pragma unroll
    for (int tc = 0; tc < 2; ++tc) {
      // build W~ B-frag: lane needs w[t = tc*32 + 8g + j][s = li]
      float wv[8];
#pragma unroll
      for (int j = 0; j < 8; ++j) {
        int src = li + 16 * (2 * (g & 1) + (j >> 2));
        float w0 = __shfl(wsc[2 * tc + 0][j & 3], src, 64);
        float w1 = __shfl(wsc[2 * tc + 1][j & 3], src, 64);
        wv[j] = (g >> 1) ? w1 : w0;
      }
      union { unsigned int u4[4]; bf16x8 v; } bw;
#pragma unroll
      for (int jj = 0; jj < 4; ++jj) bw.u4[jj] = pack_bf2(wv[2 * jj], wv[2 * jj + 1]);
      // O'[d][s] += V^T * W~ ; A-frag: d = dt*16+li, t = tc*32 + 8g + j
#pragma unroll
      for (int dt = 0; dt < 4; ++dt) {
        bf16x8 va = *(const bf16x8*)&vt32[dt * 16 + li][tc * 16 + 4 * g];
        oacc[dt] = __builtin_amdgcn_mfma_f32_16x16x32_bf16(va, bw.v, oacc[dt], 0, 0, 0);
      }
    }
  }
  // rowsum over all t for s = li (sum 4 lane-groups)
  rp += __shfl_xor(rp, 16, 64);
  rp += __shfl_xor(rp, 32, 64);
  float inv = 1.0f / fmaxf(rp, 1e-12f);
  float* aob = ao + ((size_t)bh * SS + stile * 64 + w * 16 + li) * 64;
#pragma unroll
  for (int dt = 0; dt < 4; ++dt)
#pragma unroll
    for (int r = 0; r < 4; ++r)
      aob[dt * 16 + 4 * g + r] = oacc[dt][r] * inv;
}

// ---------------- 7. output GEMM + bias + residual ----------------
__global__ __launch_bounds__(256) void k_gemm_out(const float* __restrict__ A,
                                                  const float* __restrict__ W,
                                                  const float* __restrict__ bias,
                                                  const float* __restrict__ hid,
                                                  float* __restrict__ y) {
  int n0 = blockIdx.x * 64, m0 = blockIdx.y * 64;
  __shared__ float As[16][65];
  __shared__ float Bs[16][65];
  int tid = threadIdx.x;
  int ty = tid >> 4, tx = tid & 15;
  int lar = tid >> 2, lac = (tid & 3) << 2;
  float c[4][4] = {};
  for (int k0 = 0; k0 < EE; k0 += 16) {
    float4 a4 = *(const float4*)(A + (size_t)(m0 + lar) * EE + k0 + lac);
    float4 b4 = *(const float4*)(W + (size_t)(k0 + ty) * EE + n0 + (tx << 2));
    __syncthreads();
    As[lac + 0][lar] = a4.x; As[lac + 1][lar] = a4.y;
    As[lac + 2][lar] = a4.z; As[lac + 3][lar] = a4.w;
    Bs[ty][(tx << 2) + 0] = b4.x; Bs[ty][(tx << 2) + 1] = b4.y;
    Bs[ty][(tx << 2) + 2] = b4.z; Bs[ty][(tx << 2) + 3] = b4.w;
    __syncthreads();
#pragma unroll
    for (int kk = 0; kk < 16; ++kk) {
      float a[4], b_[4];
#pragma unroll
      for (int i = 0; i < 4; ++i) a[i] = As[kk][(ty << 2) + i];
#pragma unroll
      for (int j = 0; j < 4; ++j) b_[j] = Bs[kk][(tx << 2) + j];
#pragma unroll
      for (int i = 0; i < 4; ++i)
#pragma unroll
        for (int j = 0; j < 4; ++j) c[i][j] = fmaf(a[i], b_[j], c[i][j]);
    }
  }
#pragma unroll
  for (int i = 0; i < 4; ++i) {
    int row = m0 + (ty << 2) + i;
    const float* hrow = hid + (size_t)row * EE;
    float* yrow = y + (size_t)row * EE;
#pragma unroll
    for (int j = 0; j < 4; ++j) {
      int n = n0 + (tx << 2) + j;
      yrow[n] = c[i][j] + bias[n] + hrow[n];
    }
  }
}

// ---------------- 8. LayerNorm -> float32 out ----------------
__global__ __launch_bounds__(256) void k_ln(const float* __restrict__ y,
                                            const float* __restrict__ g,
                                            const float* __restrict__ b,
                                            float* __restrict__ out) {
  int row = blockIdx.x;
  int tid = threadIdx.x;
  const float* yr = y + (size_t)row * EE;
  float v0 = yr[tid], v1 = yr[tid + 256], v2 = yr[tid + 512];
  float s1 = v0 + v1 + v2;
  float s2 = v0 * v0 + v1 * v1 + v2 * v2;
#pragma unroll
  for (int off = 32; off > 0; off >>= 1) {
    s1 += __shfl_down(s1, off, 64);
    s2 += __shfl_down(s2, off, 64);
  }
  __shared__ float r1[4], r2[4];
  if ((tid & 63) == 0) { r1[tid >> 6] = s1; r2[tid >> 6] = s2; }
  __syncthreads();
  float S1 = r1[0] + r1[1] + r1[2] + r1[3];
  float S2 = r2[0] + r2[1] + r2[2] + r2[3];
  float mu = S1 * (1.0f / 768.0f);
  float var = fmaxf(S2 * (1.0f / 768.0f) - mu * mu, 0.0f);
  float rstd = 1.0f / sqrtf(var + 1e-12f);
  float* orow = out + (size_t)row * EE;
  orow[tid]       = (v0 - mu) * rstd * g[tid]       + b[tid];
  orow[tid + 256] = (v1 - mu) * rstd * g[tid + 256] + b[tid + 256];
  orow[tid + 512] = (v2 - mu) * rstd * g[tid + 512] + b[tid + 512];
}

extern "C" void kernel_launch(void* const* d_in, const int* in_sizes, int n_in,
                              void* d_out, int out_size, void* d_ws, size_t ws_size,
                              hipStream_t stream) {
  const float* hidden = (const float*)d_in[0];
  const float* Wq = (const float*)d_in[1];
  const float* bq = (const float*)d_in[2];
  const float* Wk = (const float*)d_in[3];
  const float* bk = (const float*)d_in[4];
  const float* Wv = (const float*)d_in[5];
  const float* bv = (const float*)d_in[6];
  const float* Wo = (const float*)d_in[7];
  const float* bo = (const float*)d_in[8];
  const float* lng = (const float*)d_in[9];
  const float* lnb = (const float*)d_in[10];
  float* out = (float*)d_out;

  float* ws = (float*)d_ws;
  size_t need = (5 * NM + (size_t)BH * SS) * sizeof(float);
  if (ws_size < need) return;

  float* hs_n = ws;                       // ws0: normed hidden; top half -> q_bf; later y
  float* qf   = ws + 1 * NM;              // ws1: q fp32; later ao (attn out)
  float* kf   = ws + 2 * NM;              // ws2
  float* vf   = ws + 3 * NM;              // ws3
  float* ws4  = ws + 4 * NM;              // ws4: k_bf | v_bf
  float* cw   = ws + 5 * NM;              // [BH,S]
  unsigned int* qbf = (unsigned int*)(hs_n + NM / 2);
  unsigned int* kbf = (unsigned int*)ws4;
  unsigned int* vbf = (unsigned int*)(ws4 + NM / 2);
  float* ao = qf;    // q fp32 dead after tobf16
  float* y  = hs_n;  // q_bf dead after attention

  hipLaunchKernelGGL(k_rownorm, dim3(MM), dim3(256), 0, stream, hidden, hs_n);
  hipLaunchKernelGGL(k_gemm_qkv, dim3(EE / 64, MM / 64, 3), dim3(256), 0, stream,
                     hs_n, Wq, Wk, Wv, bq, bk, bv, qf, kf, vf);
  hipLaunchKernelGGL(k_headnorm, dim3(2 * BH * SS / 4), dim3(256), 0, stream, qf, kf);
  hipLaunchKernelGGL(k_tobf16, dim3(3 * (NM / 2) / 256), dim3(256), 0, stream,
                     qf, kf, vf, qbf, kbf, vbf);
  hipLaunchKernelGGL(k_colsum_mfma, dim3(BH, 32), dim3(256), 0, stream,
                     (const ushort*)qbf, (const ushort*)kbf, cw);
  hipLaunchKernelGGL(k_attn_mfma, dim3(BH, 32), dim3(256), 0, stream,
                     (const ushort*)qbf, (const ushort*)kbf, (const ushort*)vbf, cw, ao);
  hipLaunchKernelGGL(k_gemm_out, dim3(EE / 64, MM / 64), dim3(256), 0, stream,
                     ao, Wo, bo, hidden, y);
  hipLaunchKernelGGL(k_ln, dim3(MM), dim3(256), 0, stream, y, lng, lnb, out);
}

// Round 7
// 402.869 us; speedup vs baseline: 4.0071x; 1.5304x over previous
//
#include <hip/hip_runtime.h>
#include <hip/hip_bf16.h>
#include <math.h>

#define BB 2
#define SS 2048
#define EE 768
#define HH 12
#define DD 64
#define MM (BB*SS)          // 4096 rows
#define BH (BB*HH)          // 24 heads total
#define NM ((size_t)MM*EE)  // 3145728 elements per [B,S,E] buffer
#define WSZ ((size_t)EE*EE) // 589824 weight elements

typedef __attribute__((ext_vector_type(8))) short bf16x8;   // 8 bf16 in 4 VGPR
typedef __attribute__((ext_vector_type(4))) float f32x4;    // MFMA C/D frag

// ---------------- helpers ----------------
__device__ __forceinline__ float wave_sum64(float v) {
#pragma unroll
  for (int off = 32; off > 0; off >>= 1) v += __shfl_down(v, off, 64);
  return v;
}

// RNE pack two floats -> packed bf16 pair (lo = x)
__device__ __forceinline__ unsigned int pack_bf2(float x, float y) {
  unsigned int a = __float_as_uint(x), b = __float_as_uint(y);
  a += 0x7fffu + ((a >> 16) & 1u);
  b += 0x7fffu + ((b >> 16) & 1u);
  return (a >> 16) | (b & 0xffff0000u);
}
__device__ __forceinline__ ushort bf16_1(float x) {
  unsigned int u = __float_as_uint(x);
  u += 0x7fffu + ((u >> 16) & 1u);
  return (ushort)(u >> 16);
}

// score(x) = exp(-acos(clip(x))^2), fast: A&S 4.4.45 4-term (|err acos| <= 6.8e-5)
__device__ __forceinline__ float score_fast(float x) {
  float a = fminf(fabsf(x), 0.9999999f);
  float r = sqrtf(1.0f - a);
  float p = fmaf(a, fmaf(a, fmaf(a, -0.0187293f, 0.0742610f), -0.2121144f), 1.5707288f);
  float gp = r * p;
  float g = (x < 0.0f) ? (3.14159274f - gp) : gp;
  return __expf(-g * g);
}

// ---------------- 1. row l2-norm over E -> bf16 ----------------
__global__ __launch_bounds__(256) void k_rownorm(const float* __restrict__ x,
                                                 ushort* __restrict__ o) {
  int row = blockIdx.x;
  int tid = threadIdx.x;
  const float* xr = x + (size_t)row * EE;
  ushort* orow = o + (size_t)row * EE;
  float v0 = xr[tid], v1 = xr[tid + 256], v2 = xr[tid + 512];
  float ss = v0 * v0 + v1 * v1 + v2 * v2;
  ss = wave_sum64(ss);
  __shared__ float red[4];
  if ((tid & 63) == 0) red[tid >> 6] = ss;
  __syncthreads();
  float tot = red[0] + red[1] + red[2] + red[3];
  float sc = 1.0f / fmaxf(sqrtf(tot), 1e-12f);
  orow[tid]       = bf16_1(v0 * sc);
  orow[tid + 256] = bf16_1(v1 * sc);
  orow[tid + 512] = bf16_1(v2 * sc);
}

// ---------------- 2. weight transpose -> bf16 Wt[n][k] ----------------
__global__ __launch_bounds__(256) void k_transp(const float* __restrict__ Wq,
                                                const float* __restrict__ Wk,
                                                const float* __restrict__ Wv,
                                                const float* __restrict__ Wo,
                                                ushort* __restrict__ wt) {
  int z = blockIdx.z;
  const float* W = (z == 0) ? Wq : (z == 1) ? Wk : (z == 2) ? Wv : Wo;
  ushort* dst = wt + (size_t)z * WSZ;
  int n0 = blockIdx.x * 64, k0 = blockIdx.y * 64;
  __shared__ float t[64][65];
  int tid = threadIdx.x;
  int r4 = tid >> 4, c4 = (tid & 15) * 4;
#pragma unroll
  for (int i = 0; i < 4; ++i) {
    float4 v = *(const float4*)(W + (size_t)(k0 + i * 16 + r4) * EE + n0 + c4);
    t[i * 16 + r4][c4 + 0] = v.x; t[i * 16 + r4][c4 + 1] = v.y;
    t[i * 16 + r4][c4 + 2] = v.z; t[i * 16 + r4][c4 + 3] = v.w;
  }
  __syncthreads();
  int nr = tid >> 3, c8 = (tid & 7) * 8;
#pragma unroll
  for (int j = 0; j < 2; ++j) {
    int n = nr + j * 32;
    unsigned int p[4];
#pragma unroll
    for (int e = 0; e < 4; ++e)
      p[e] = pack_bf2(t[c8 + 2 * e][n], t[c8 + 2 * e + 1][n]);
    uint4 pv; pv.x = p[0]; pv.y = p[1]; pv.z = p[2]; pv.w = p[3];
    *(uint4*)(dst + (size_t)(n0 + n) * EE + k0 + c8) = pv;
  }
}

// ---------------- 3. QKV GEMM (bf16 MFMA): q,k fp32 head-major; v bf16 ----------------
__global__ __launch_bounds__(256) void k_gemm_qkv_mfma(
    const ushort* __restrict__ hsb,   // [4096][768] bf16
    const ushort* __restrict__ wt,    // 3 x [768][768] bf16 transposed
    const float* __restrict__ b0, const float* __restrict__ b1, const float* __restrict__ b2,
    float* __restrict__ qf, float* __restrict__ kf, ushort* __restrict__ vb) {
  int z = blockIdx.z;
  const ushort* W = wt + (size_t)z * WSZ;
  const float* bias = (z == 0) ? b0 : (z == 1) ? b1 : b2;
  int n0 = blockIdx.x * 64, m0 = blockIdx.y * 64;
  int tid = threadIdx.x, w = tid >> 6, l = tid & 63, li = l & 15, g = l >> 4;
  const ushort* arow = hsb + (size_t)(m0 + w * 16 + li) * EE;
  const ushort* br0 = W + (size_t)(n0 + 0 * 16 + li) * EE;
  const ushort* br1 = W + (size_t)(n0 + 1 * 16 + li) * EE;
  const ushort* br2 = W + (size_t)(n0 + 2 * 16 + li) * EE;
  const ushort* br3 = W + (size_t)(n0 + 3 * 16 + li) * EE;
  f32x4 acc[4];
#pragma unroll
  for (int u = 0; u < 4; ++u) acc[u] = (f32x4){0.f, 0.f, 0.f, 0.f};
  for (int k0 = 0; k0 < EE; k0 += 64) {
    bf16x8 a0 = *(const bf16x8*)(arow + k0 + 8 * g);
    bf16x8 a1 = *(const bf16x8*)(arow + k0 + 32 + 8 * g);
    bf16x8 c00 = *(const bf16x8*)(br0 + k0 + 8 * g);
    bf16x8 c01 = *(const bf16x8*)(br0 + k0 + 32 + 8 * g);
    bf16x8 c10 = *(const bf16x8*)(br1 + k0 + 8 * g);
    bf16x8 c11 = *(const bf16x8*)(br1 + k0 + 32 + 8 * g);
    bf16x8 c20 = *(const bf16x8*)(br2 + k0 + 8 * g);
    bf16x8 c21 = *(const bf16x8*)(br2 + k0 + 32 + 8 * g);
    bf16x8 c30 = *(const bf16x8*)(br3 + k0 + 8 * g);
    bf16x8 c31 = *(const bf16x8*)(br3 + k0 + 32 + 8 * g);
    acc[0] = __builtin_amdgcn_mfma_f32_16x16x32_bf16(a0, c00, acc[0], 0, 0, 0);
    acc[0] = __builtin_amdgcn_mfma_f32_16x16x32_bf16(a1, c01, acc[0], 0, 0, 0);
    acc[1] = __builtin_amdgcn_mfma_f32_16x16x32_bf16(a0, c10, acc[1], 0, 0, 0);
    acc[1] = __builtin_amdgcn_mfma_f32_16x16x32_bf16(a1, c11, acc[1], 0, 0, 0);
    acc[2] = __builtin_amdgcn_mfma_f32_16x16x32_bf16(a0, c20, acc[2], 0, 0, 0);
    acc[2] = __builtin_amdgcn_mfma_f32_16x16x32_bf16(a1, c21, acc[2], 0, 0, 0);
    acc[3] = __builtin_amdgcn_mfma_f32_16x16x32_bf16(a0, c30, acc[3], 0, 0, 0);
    acc[3] = __builtin_amdgcn_mfma_f32_16x16x32_bf16(a1, c31, acc[3], 0, 0, 0);
  }
  int m_base = m0 + w * 16 + 4 * g;
  int h = n0 >> 6;
#pragma unroll
  for (int u = 0; u < 4; ++u) {
    int d = u * 16 + li;
    float bia = bias[n0 + u * 16 + li];
#pragma unroll
    for (int r = 0; r < 4; ++r) {
      int m = m_base + r;
      int b_ = m >> 11, s = m & 2047;
      size_t off = (((size_t)b_ * HH + h) * SS + s) * DD + d;
      float val = acc[u][r] + bia;
      if (z == 0) qf[off] = val;
      else if (z == 1) kf[off] = val;
      else vb[off] = bf16_1(val);
    }
  }
}

// ---------------- 4. per-head l2norm of q,k -> bf16 ----------------
__global__ __launch_bounds__(256) void k_headnorm_bf(const float* __restrict__ qf,
                                                     const float* __restrict__ kf,
                                                     ushort* __restrict__ qb,
                                                     ushort* __restrict__ kb) {
  int gid = blockIdx.x * 4 + (threadIdx.x >> 6);
  int lane = threadIdx.x & 63;
  const int NV = BH * SS;
  bool isq = gid < NV;
  size_t idx = isq ? (size_t)gid : (size_t)(gid - NV);
  const float* p = (isq ? qf : kf) + idx * DD;
  ushort* o = (isq ? qb : kb) + idx * DD;
  float val = p[lane];
  float ss = val * val;
#pragma unroll
  for (int off = 32; off > 0; off >>= 1) ss += __shfl_xor(ss, off, 64);
  o[lane] = bf16_1(val / fmaxf(sqrtf(ss), 1e-12f));
}

// ---------------- 5. colsum pass (MFMA) -> cw = rsqrt(colsum) ----------------
__global__ __launch_bounds__(256) void k_colsum_mfma(const ushort* __restrict__ qbf,
                                                     const ushort* __restrict__ kbf,
                                                     float* __restrict__ cwout) {
  int bh = blockIdx.x, ttile = blockIdx.y;
  __shared__ __align__(16) ushort K_lds[64][72];
  __shared__ float scs[4][4][16];
  int tid = threadIdx.x;
  int w = tid >> 6, l = tid & 63;
  int li = l & 15, g = l >> 4;
  const ushort* kt = kbf + ((size_t)bh * SS + ttile * 64) * 64;
#pragma unroll
  for (int i = 0; i < 2; ++i) {
    int idx = i * 256 + tid; int t = idx >> 3, c = idx & 7;
    *(bf16x8*)&K_lds[t][c * 8] = *(const bf16x8*)(kt + t * 64 + c * 8);
  }
  __syncthreads();
  bf16x8 kb[4][2];
#pragma unroll
  for (int u = 0; u < 4; ++u)
#pragma unroll
    for (int kc = 0; kc < 2; ++kc)
      kb[u][kc] = *(const bf16x8*)&K_lds[u * 16 + li][kc * 32 + 8 * g];
  float cacc[4] = {0.f, 0.f, 0.f, 0.f};
  for (int it = 0; it < 32; ++it) {
    int s0 = (it * 4 + w) * 16;
    const ushort* qrow = qbf + ((size_t)bh * SS + s0 + li) * 64;
    bf16x8 qa0 = *(const bf16x8*)(qrow + 0 * 32 + 8 * g);
    bf16x8 qa1 = *(const bf16x8*)(qrow + 1 * 32 + 8 * g);
#pragma unroll
    for (int u = 0; u < 4; ++u) {
      f32x4 cf = {0.f, 0.f, 0.f, 0.f};
      cf = __builtin_amdgcn_mfma_f32_16x16x32_bf16(qa0, kb[u][0], cf, 0, 0, 0);
      cf = __builtin_amdgcn_mfma_f32_16x16x32_bf16(qa1, kb[u][1], cf, 0, 0, 0);
      cacc[u] += score_fast(cf[0]) + score_fast(cf[1]) +
                 score_fast(cf[2]) + score_fast(cf[3]);
    }
  }
#pragma unroll
  for (int u = 0; u < 4; ++u) {
    cacc[u] += __shfl_xor(cacc[u], 16, 64);
    cacc[u] += __shfl_xor(cacc[u], 32, 64);
  }
  if (l < 16) {
#pragma unroll
    for (int u = 0; u < 4; ++u) scs[w][u][l] = cacc[u];
  }
  __syncthreads();
  if (tid < 64) {
    int t16 = tid & 15, u = tid >> 4;
    float s_ = scs[0][u][t16] + scs[1][u][t16] + scs[2][u][t16] + scs[3][u][t16];
    cwout[(size_t)bh * SS + ttile * 64 + u * 16 + t16] = rsqrtf(s_);
  }
}

// ---------------- 6. attention pass (MFMA) -> bf16 attn-out ----------------
__global__ __launch_bounds__(256) void k_attn_mfma(const ushort* __restrict__ qbf,
                                                   const ushort* __restrict__ kbf,
                                                   const ushort* __restrict__ vbf,
                                                   const float* __restrict__ cw,
                                                   ushort* __restrict__ aobf) {
  int bh = blockIdx.x, stile = blockIdx.y;
  __shared__ __align__(16) ushort K_lds[64][72];
  __shared__ __align__(16) unsigned int vt32[64][36];
  __shared__ float cw_lds[64];
  int tid = threadIdx.x;
  int w = tid >> 6, l = tid & 63;
  int li = l & 15, g = l >> 4;
  const ushort* qrow = qbf + ((size_t)bh * SS + stile * 64 + w * 16 + li) * 64;
  bf16x8 qb0 = *(const bf16x8*)(qrow + 0 * 32 + 8 * g);
  bf16x8 qb1 = *(const bf16x8*)(qrow + 1 * 32 + 8 * g);
  f32x4 oacc[4];
#pragma unroll
  for (int dt = 0; dt < 4; ++dt) oacc[dt] = (f32x4){0.f, 0.f, 0.f, 0.f};
  float rp = 0.f;
  for (int tt = 0; tt < 32; ++tt) {
    const ushort* kt = kbf + ((size_t)bh * SS + tt * 64) * 64;
    const ushort* vt = vbf + ((size_t)bh * SS + tt * 64) * 64;
    __syncthreads();
#pragma unroll
    for (int i = 0; i < 2; ++i) {
      int idx = i * 256 + tid; int t = idx >> 3, c = idx & 7;
      *(bf16x8*)&K_lds[t][c * 8] = *(const bf16x8*)(kt + t * 64 + c * 8);
    }
    {
      int tp = tid & 31, dc = tid >> 5;
      const ushort* r0 = vt + (2 * tp) * 64 + dc * 8;
      bf16x8 a = *(const bf16x8*)r0;
      bf16x8 b = *(const bf16x8*)(r0 + 64);
#pragma unroll
      for (int dj = 0; dj < 8; ++dj)
        vt32[dc * 8 + dj][tp] =
            (unsigned int)(unsigned short)a[dj] |
            ((unsigned int)(unsigned short)b[dj] << 16);
    }
    if (tid < 64) cw_lds[tid] = cw[(size_t)bh * SS + tt * 64 + tid];
    __syncthreads();
    f32x4 wsc[4];
#pragma unroll
    for (int u = 0; u < 4; ++u) {
      bf16x8 ka0 = *(const bf16x8*)&K_lds[u * 16 + li][0 * 32 + 8 * g];
      bf16x8 ka1 = *(const bf16x8*)&K_lds[u * 16 + li][1 * 32 + 8 * g];
      f32x4 cf = {0.f, 0.f, 0.f, 0.f};
      cf = __builtin_amdgcn_mfma_f32_16x16x32_bf16(ka0, qb0, cf, 0, 0, 0);
      cf = __builtin_amdgcn_mfma_f32_16x16x32_bf16(ka1, qb1, cf, 0, 0, 0);
#pragma unroll
      for (int r = 0; r < 4; ++r) {
        float sc = score_fast(cf[r]) * cw_lds[u * 16 + 4 * g + r];
        cf[r] = sc;
        rp += sc;
      }
      wsc[u] = cf;
    }
#pragma unroll
    for (int tc = 0; tc < 2; ++tc) {
      float wv[8];
#pragma unroll
      for (int j = 0; j < 8; ++j) {
        int src = li + 16 * (2 * (g & 1) + (j >> 2));
        float w0 = __shfl(wsc[2 * tc + 0][j & 3], src, 64);
        float w1 = __shfl(wsc[2 * tc + 1][j & 3], src, 64);
        wv[j] = (g >> 1) ? w1 : w0;
      }
      union { unsigned int u4[4]; bf16x8 v; } bw;
#pragma unroll
      for (int jj = 0; jj < 4; ++jj) bw.u4[jj] = pack_bf2(wv[2 * jj], wv[2 * jj + 1]);
#pragma unroll
      for (int dt = 0; dt < 4; ++dt) {
        bf16x8 va = *(const bf16x8*)&vt32[dt * 16 + li][tc * 16 + 4 * g];
        oacc[dt] = __builtin_amdgcn_mfma_f32_16x16x32_bf16(va, bw.v, oacc[dt], 0, 0, 0);
      }
    }
  }
  rp += __shfl_xor(rp, 16, 64);
  rp += __shfl_xor(rp, 32, 64);
  float inv = 1.0f / fmaxf(rp, 1e-12f);
  unsigned int* a32 =
      (unsigned int*)(aobf + ((size_t)bh * SS + stile * 64 + w * 16 + li) * 64);
#pragma unroll
  for (int dt = 0; dt < 4; ++dt) {
    unsigned int p0 = pack_bf2(oacc[dt][0] * inv, oacc[dt][1] * inv);
    unsigned int p1 = pack_bf2(oacc[dt][2] * inv, oacc[dt][3] * inv);
    uint2 pv; pv.x = p0; pv.y = p1;
    *(uint2*)&a32[dt * 8 + 2 * g] = pv;
  }
}

// ---------------- 7. output GEMM (bf16 MFMA) + bias + residual ----------------
__global__ __launch_bounds__(256) void k_gemm_out_mfma(
    const ushort* __restrict__ aob,   // [4096][768] bf16
    const ushort* __restrict__ Wt,    // [768][768] bf16 transposed
    const float* __restrict__ bias,
    const float* __restrict__ hid,
    float* __restrict__ y) {
  int n0 = blockIdx.x * 64, m0 = blockIdx.y * 64;
  int tid = threadIdx.x, w = tid >> 6, l = tid & 63, li = l & 15, g = l >> 4;
  const ushort* arow = aob + (size_t)(m0 + w * 16 + li) * EE;
  const ushort* br0 = Wt + (size_t)(n0 + 0 * 16 + li) * EE;
  const ushort* br1 = Wt + (size_t)(n0 + 1 * 16 + li) * EE;
  const ushort* br2 = Wt + (size_t)(n0 + 2 * 16 + li) * EE;
  const ushort* br3 = Wt + (size_t)(n0 + 3 * 16 + li) * EE;
  f32x4 acc[4];
#pragma unroll
  for (int u = 0; u < 4; ++u) acc[u] = (f32x4){0.f, 0.f, 0.f, 0.f};
  for (int k0 = 0; k0 < EE; k0 += 64) {
    bf16x8 a0 = *(const bf16x8*)(arow + k0 + 8 * g);
    bf16x8 a1 = *(const bf16x8*)(arow + k0 + 32 + 8 * g);
    bf16x8 c00 = *(const bf16x8*)(br0 + k0 + 8 * g);
    bf16x8 c01 = *(const bf16x8*)(br0 + k0 + 32 + 8 * g);
    bf16x8 c10 = *(const bf16x8*)(br1 + k0 + 8 * g);
    bf16x8 c11 = *(const bf16x8*)(br1 + k0 + 32 + 8 * g);
    bf16x8 c20 = *(const bf16x8*)(br2 + k0 + 8 * g);
    bf16x8 c21 = *(const bf16x8*)(br2 + k0 + 32 + 8 * g);
    bf16x8 c30 = *(const bf16x8*)(br3 + k0 + 8 * g);
    bf16x8 c31 = *(const bf16x8*)(br3 + k0 + 32 + 8 * g);
    acc[0] = __builtin_amdgcn_mfma_f32_16x16x32_bf16(a0, c00, acc[0], 0, 0, 0);
    acc[0] = __builtin_amdgcn_mfma_f32_16x16x32_bf16(a1, c01, acc[0], 0, 0, 0);
    acc[1] = __builtin_amdgcn_mfma_f32_16x16x32_bf16(a0, c10, acc[1], 0, 0, 0);
    acc[1] = __builtin_amdgcn_mfma_f32_16x16x32_bf16(a1, c11, acc[1], 0, 0, 0);
    acc[2] = __builtin_amdgcn_mfma_f32_16x16x32_bf16(a0, c20, acc[2], 0, 0, 0);
    acc[2] = __builtin_amdgcn_mfma_f32_16x16x32_bf16(a1, c21, acc[2], 0, 0, 0);
    acc[3] = __builtin_amdgcn_mfma_f32_16x16x32_bf16(a0, c30, acc[3], 0, 0, 0);
    acc[3] = __builtin_amdgcn_mfma_f32_16x16x32_bf16(a1, c31, acc[3], 0, 0, 0);
  }
  int m_base = m0 + w * 16 + 4 * g;
#pragma unroll
  for (int u = 0; u < 4; ++u) {
    int n = n0 + u * 16 + li;
    float bia = bias[n];
#pragma unroll
    for (int r = 0; r < 4; ++r) {
      int m = m_base + r;
      y[(size_t)m * EE + n] = acc[u][r] + bia + hid[(size_t)m * EE + n];
    }
  }
}

// ---------------- 8. LayerNorm -> float32 out ----------------
__global__ __launch_bounds__(256) void k_ln(const float* __restrict__ y,
                                            const float* __restrict__ g,
                                            const float* __restrict__ b,
                                            float* __restrict__ out) {
  int row = blockIdx.x;
  int tid = threadIdx.x;
  const float* yr = y + (size_t)row * EE;
  float v0 = yr[tid], v1 = yr[tid + 256], v2 = yr[tid + 512];
  float s1 = v0 + v1 + v2;
  float s2 = v0 * v0 + v1 * v1 + v2 * v2;
#pragma unroll
  for (int off = 32; off > 0; off >>= 1) {
    s1 += __shfl_down(s1, off, 64);
    s2 += __shfl_down(s2, off, 64);
  }
  __shared__ float r1[4], r2[4];
  if ((tid & 63) == 0) { r1[tid >> 6] = s1; r2[tid >> 6] = s2; }
  __syncthreads();
  float S1 = r1[0] + r1[1] + r1[2] + r1[3];
  float S2 = r2[0] + r2[1] + r2[2] + r2[3];
  float mu = S1 * (1.0f / 768.0f);
  float var = fmaxf(S2 * (1.0f / 768.0f) - mu * mu, 0.0f);
  float rstd = 1.0f / sqrtf(var + 1e-12f);
  float* orow = out + (size_t)row * EE;
  orow[tid]       = (v0 - mu) * rstd * g[tid]       + b[tid];
  orow[tid + 256] = (v1 - mu) * rstd * g[tid + 256] + b[tid + 256];
  orow[tid + 512] = (v2 - mu) * rstd * g[tid + 512] + b[tid + 512];
}

extern "C" void kernel_launch(void* const* d_in, const int* in_sizes, int n_in,
                              void* d_out, int out_size, void* d_ws, size_t ws_size,
                              hipStream_t stream) {
  const float* hidden = (const float*)d_in[0];
  const float* Wq = (const float*)d_in[1];
  const float* bq = (const float*)d_in[2];
  const float* Wk = (const float*)d_in[3];
  const float* bk = (const float*)d_in[4];
  const float* Wv = (const float*)d_in[5];
  const float* bv = (const float*)d_in[6];
  const float* Wo = (const float*)d_in[7];
  const float* bo = (const float*)d_in[8];
  const float* lng = (const float*)d_in[9];
  const float* lnb = (const float*)d_in[10];
  float* out = (float*)d_out;

  float* ws = (float*)d_ws;
  size_t need = (5 * NM + (size_t)BH * SS) * sizeof(float);
  if (ws_size < need) return;

  // ws0: hs_bf (NM bf16 = NM/2 floats) + Wt (4*WSZ bf16 = 1.18M floats) -- fits in NM
  ushort* hsb = (ushort*)ws;
  ushort* wt  = (ushort*)(ws + NM / 2);
  float* qf   = ws + 1 * NM;   // fp32 q; dead after headnorm -> reused as ao_bf
  float* kf   = ws + 2 * NM;   // fp32 k; dead after headnorm -> reused as y
  unsigned int* qbf = (unsigned int*)(ws + 3 * NM);
  unsigned int* kbf = (unsigned int*)(ws + 4 * NM);
  unsigned int* vbf = (unsigned int*)(ws + 4 * NM + NM / 2);
  float* cw = ws + 5 * NM;
  ushort* aobf = (ushort*)qf;
  float* y = kf;

  hipLaunchKernelGGL(k_rownorm, dim3(MM), dim3(256), 0, stream, hidden, hsb);
  hipLaunchKernelGGL(k_transp, dim3(EE / 64, EE / 64, 4), dim3(256), 0, stream,
                     Wq, Wk, Wv, Wo, wt);
  hipLaunchKernelGGL(k_gemm_qkv_mfma, dim3(EE / 64, MM / 64, 3), dim3(256), 0, stream,
                     hsb, wt, bq, bk, bv, qf, kf, (ushort*)vbf);
  hipLaunchKernelGGL(k_headnorm_bf, dim3(2 * BH * SS / 4), dim3(256), 0, stream,
                     qf, kf, (ushort*)qbf, (ushort*)kbf);
  hipLaunchKernelGGL(k_colsum_mfma, dim3(BH, 32), dim3(256), 0, stream,
                     (const ushort*)qbf, (const ushort*)kbf, cw);
  hipLaunchKernelGGL(k_attn_mfma, dim3(BH, 32), dim3(256), 0, stream,
                     (const ushort*)qbf, (const ushort*)kbf, (const ushort*)vbf, cw, aobf);
  hipLaunchKernelGGL(k_gemm_out_mfma, dim3(EE / 64, MM / 64), dim3(256), 0, stream,
                     aobf, wt + 3 * WSZ, bo, hidden, y);
  hipLaunchKernelGGL(k_ln, dim3(MM), dim3(256), 0, stream, y, lng, lnb, out);
}